// Round 5
// baseline (157.063 us; speedup 1.0000x reference)
//
#include <hip/hip_runtime.h>
#include <hip/hip_bf16.h>

#define EPS 1e-6f

typedef float  f32x4  __attribute__((ext_vector_type(4)));
typedef __bf16 bf16x8 __attribute__((ext_vector_type(8)));

// ---------- helpers ----------
static __device__ __forceinline__ unsigned short f2bf(float f) {
    unsigned int x = __float_as_uint(f);
    unsigned int r = (x + 0x7FFFu + ((x >> 16) & 1u)) >> 16;   // RNE
    return (unsigned short)r;
}

// ---------- kernel 1: row stats (fp32) + bf16 conversion, both matrices ----------
__global__ __launch_bounds__(256) void prep_kernel(
    const float* __restrict__ protos, const float* __restrict__ querys,
    unsigned short* __restrict__ pb, unsigned short* __restrict__ qb,
    float* __restrict__ p_sq, float* __restrict__ p_sum,
    float* __restrict__ q_sq, float* __restrict__ q_sum)
{
    const int b   = blockIdx.x;
    const int tid = threadIdx.x;
    const float* src; unsigned short* dst; float* rsq; float* rsum;
    if (b < 1024) {
        src = protos + (size_t)b * 1024; dst = pb + (size_t)b * 1024;
        rsq = p_sq + b; rsum = p_sum + b;
    } else {
        const int r = b - 1024;
        src = querys + (size_t)r * 1024; dst = qb + (size_t)r * 1024;
        rsq = q_sq + r; rsum = q_sum + r;
    }

    const float4 v = reinterpret_cast<const float4*>(src)[tid];
    float s  = v.x + v.y + v.z + v.w;
    float ss = v.x * v.x + v.y * v.y + v.z * v.z + v.w * v.w;

    ushort4 o;
    o.x = f2bf(v.x); o.y = f2bf(v.y); o.z = f2bf(v.z); o.w = f2bf(v.w);
    reinterpret_cast<ushort4*>(dst)[tid] = o;

    #pragma unroll
    for (int m = 32; m >= 1; m >>= 1) {
        s  += __shfl_xor(s, m, 64);
        ss += __shfl_xor(ss, m, 64);
    }
    __shared__ float red[8];
    const int wave = tid >> 6;
    if ((tid & 63) == 0) { red[wave] = s; red[4 + wave] = ss; }
    __syncthreads();
    if (tid == 0) {
        *rsum = red[0] + red[1] + red[2] + red[3];
        *rsq  = red[4] + red[5] + red[6] + red[7];
    }
}

// ---------- kernel 2: fused GEMM + softmax/entropy, row-panel, LDS-staged B ----------
// grid = 256 blocks x 512 threads (8 waves). Block owns rows br*32..+31, ALL 1024 cols.
// Wave w owns cols w*128..+127 (2 m-frags x 8 n-frags of 16x16x32 MFMA).
// B (prototypes) double-buffered in LDS via global_load_lds (2 x 64 KiB, BK=32);
// A (queries, 2 KB/step) direct-from-global with register double-buffer.
// T3-minimum 2-phase: STAGE(next)+LOADA(next) issued BEFORE ds_read+MFMA(cur);
// one drain+barrier per K-step.
__global__ __launch_bounds__(512, 2) void fused2_kernel(
    const unsigned short* __restrict__ qb,   // [8192][1024] bf16 bits
    const unsigned short* __restrict__ pb,   // [1024][1024] bf16 bits
    const float* __restrict__ q_sq, const float* __restrict__ q_sum,
    const float* __restrict__ p_sq, const float* __restrict__ p_sum,
    float* __restrict__ post, float* __restrict__ c_out, float* __restrict__ h_out)
{
    __shared__ unsigned short Bs[2][1024 * 32];   // 2 x 64 KiB, [col][k] rows of 64 B
    __shared__ float se_l[8][32];
    __shared__ float te_l[8][32];
    __shared__ float mx_l[8][32];
    __shared__ float inv_l[32];

    const int tid  = threadIdx.x;
    const int w    = tid >> 6;
    const int lane = tid & 63;
    const int l15  = lane & 15;
    const int l4   = lane >> 4;
    const int row0 = blockIdx.x * 32;
    const int col0 = w * 128;

// stage 64 KiB B-tile (all 1024 cols x 32 k) for K-offset KK into Bs[BUF]
// linear chunk (rr*512+tid): LDS byte = lin*16 (wave-uniform base + lane*16 OK);
// source = pb[col=lin>>2][KK + (lin&3)*8]
#define STAGE(BUF, KK) do {                                                              \
    _Pragma("unroll")                                                                    \
    for (int rr = 0; rr < 8; ++rr) {                                                     \
        const int lin = rr * 512 + tid;                                                  \
        const unsigned short* srcp = pb + (size_t)(lin >> 2) * 1024 + (KK) + (lin & 3) * 8; \
        __builtin_amdgcn_global_load_lds((const __attribute__((address_space(1))) void*)srcp, \
            (__attribute__((address_space(3))) void*)(&Bs[BUF][lin * 8]), 16, 0, 0);     \
    }                                                                                    \
} while (0)

#define LOADA(A, KK) do {                                                                \
    A[0] = *reinterpret_cast<const bf16x8*>(qb + (size_t)(row0 + l15) * 1024 + (KK) + l4 * 8);      \
    A[1] = *reinterpret_cast<const bf16x8*>(qb + (size_t)(row0 + 16 + l15) * 1024 + (KK) + l4 * 8); \
} while (0)

    f32x4 acc[2][8];
    #pragma unroll
    for (int m = 0; m < 2; ++m)
        #pragma unroll
        for (int n = 0; n < 8; ++n)
            acc[m][n] = (f32x4)0.0f;

    bf16x8 aC[2], aN[2];

    // prologue: stage k=0 tile, load A k=0
    STAGE(0, 0);
    LOADA(aC, 0);
    __syncthreads();            // compiler drains vmcnt before s_barrier

    int cur = 0;
    #pragma unroll 1
    for (int kk = 0; kk < 1024; kk += 32) {
        if (kk < 992) {                 // issue next-tile loads BEFORE compute (T3 2-phase)
            STAGE(cur ^ 1, kk + 32);
            LOADA(aN, kk + 32);
        }

        bf16x8 b[8];
        #pragma unroll
        for (int n = 0; n < 8; ++n)
            b[n] = *reinterpret_cast<const bf16x8*>(&Bs[cur][(col0 + n * 16 + l15) * 32 + l4 * 8]);

        #pragma unroll
        for (int m = 0; m < 2; ++m)
            #pragma unroll
            for (int n = 0; n < 8; ++n)
                acc[m][n] = __builtin_amdgcn_mfma_f32_16x16x32_bf16(aC[m], b[n], acc[m][n], 0, 0, 0);

        if (kk < 992) { aC[0] = aN[0]; aC[1] = aN[1]; }
        __syncthreads();                // drains vmcnt (staged loads) + lgkm, once per K-step
        cur ^= 1;
    }

#undef STAGE
#undef LOADA

    // ---- epilogue: dist -> e = exp(-dist) in-register; per-row softmax stats ----
    const float dee = 1024.0f * EPS * EPS;

    float ps[8], pm[8];
    #pragma unroll
    for (int n = 0; n < 8; ++n) {
        const int c = col0 + n * 16 + l15;
        ps[n] = p_sq[c];
        pm[n] = p_sum[c];
    }

    #pragma unroll
    for (int m = 0; m < 2; ++m) {
        #pragma unroll
        for (int r = 0; r < 4; ++r) {
            const int lr = m * 16 + l4 * 4 + r;           // block-row 0..31
            const float qs = q_sq[row0 + lr], qm = q_sum[row0 + lr];
            float se = 0.0f, te = 0.0f, mx = 0.0f;
            #pragma unroll
            for (int n = 0; n < 8; ++n) {
                const float cross = acc[m][n][r];
                const float sq = qs + ps[n] - 2.0f * cross + 2.0f * EPS * (qm - pm[n]) + dee;
                const float dist = sqrtf(fmaxf(sq, 0.0f));
                const float e = __expf(-dist);
                acc[m][n][r] = e;
                se += e;
                te += e * dist;
                mx = fmaxf(mx, e);
            }
            #pragma unroll
            for (int msk = 8; msk >= 1; msk >>= 1) {      // reduce over l15 (16 cols/lanegrp)
                se += __shfl_xor(se, msk, 64);
                te += __shfl_xor(te, msk, 64);
                mx = fmaxf(mx, __shfl_xor(mx, msk, 64));
            }
            if (l15 == 0) {
                se_l[w][lr] = se;
                te_l[w][lr] = te;
                mx_l[w][lr] = mx;
            }
        }
    }
    __syncthreads();

    if (tid < 32) {
        float s = 0.0f, t = 0.0f, mx = 0.0f;
        #pragma unroll
        for (int ww = 0; ww < 8; ++ww) {
            s += se_l[ww][tid];
            t += te_l[ww][tid];
            mx = fmaxf(mx, mx_l[ww][tid]);
        }
        const float inv = 1.0f / s;
        inv_l[tid] = inv;
        c_out[row0 + tid] = mx * inv;
        h_out[row0 + tid] = logf(s) + t * inv;            // h = t/s + log s
    }
    __syncthreads();

    // ---- normalized store (single pass, no intermediate) ----
    #pragma unroll
    for (int m = 0; m < 2; ++m) {
        #pragma unroll
        for (int r = 0; r < 4; ++r) {
            const int lr = m * 16 + l4 * 4 + r;
            const float inv = inv_l[lr];
            #pragma unroll
            for (int n = 0; n < 8; ++n) {
                post[(size_t)(row0 + lr) * 1024 + col0 + n * 16 + l15] = acc[m][n][r] * inv;
            }
        }
    }
}

// ---------- launcher ----------
extern "C" void kernel_launch(void* const* d_in, const int* in_sizes, int n_in,
                              void* d_out, int out_size, void* d_ws, size_t ws_size,
                              hipStream_t stream) {
    const float* protos = (const float*)d_in[0];  // [1024,1024]
    const float* querys = (const float*)d_in[1];  // [8192,1024]

    float* out   = (float*)d_out;
    float* post  = out;                            // 8192*1024
    float* c_out = out + (size_t)8192 * 1024;      // 8192
    float* h_out = c_out + 8192;                   // 8192

    char* ws = (char*)d_ws;
    unsigned short* qb = (unsigned short*)ws;  ws += (size_t)8192 * 1024 * 2;
    unsigned short* pb = (unsigned short*)ws;  ws += (size_t)1024 * 1024 * 2;
    float* q_sq  = (float*)ws;  ws += 8192 * 4;
    float* q_sum = (float*)ws;  ws += 8192 * 4;
    float* p_sq  = (float*)ws;  ws += 1024 * 4;
    float* p_sum = (float*)ws;  ws += 1024 * 4;

    prep_kernel<<<9216, 256, 0, stream>>>(protos, querys, pb, qb, p_sq, p_sum, q_sq, q_sum);
    fused2_kernel<<<256, 512, 0, stream>>>(qb, pb, q_sq, q_sum, p_sq, p_sum,
                                           post, c_out, h_out);
}